// Round 2
// 74.613 us; speedup vs baseline: 1.0270x; 1.0270x over previous
//
#include <hip/hip_runtime.h>

#define L_SEQ   512
#define NHEADS_ 8
#define HEADDIM_ 128
#define QKD     16
#define DINNER  1024
#define EPS_F   1e-3f
#define STD_F   0.0078125f   // 1/sqrt(2*512*16) = 1/128

// LDS layout for KS[t_local][l]: addr = t*KS_ROW + (l>>5)*33 + (l&31)
// KS_ROW=529 (529%32=17); phase-A stores and phase-B reads both <=2-way (free).
#define KS_ROW  529

typedef __attribute__((ext_vector_type(8))) short  short8;
typedef __attribute__((ext_vector_type(4))) float  floatx4;
typedef __attribute__((ext_vector_type(2))) float  float2v;

// cos(2*pi*rev): v_cos_f32 takes revolutions; reduce to [0,1) first.
__device__ __forceinline__ float cosrev(float rev) {
    float r = rev - floorf(rev);
    return __builtin_amdgcn_cosf(r);
}

// 2*cos(2*pi*a) for tiny |a| (<= ~0.008 rev): even poly, err ~2e-12.
__device__ __forceinline__ float two_cos_small(float a) {
    float x = a * a;
    return fmaf(fmaf(x, 129.8787876f, -39.4784176f), x, 2.0f);
}

// float -> bf16 bits, round-to-nearest-even
__device__ __forceinline__ unsigned short f2bf_rne(float x) {
    union { float f; unsigned int u; } v;
    v.f = x;
    unsigned int r = v.u + 0x7fffu + ((v.u >> 16) & 1u);
    return (unsigned short)(r >> 16);
}
// cheap round-half-up
__device__ __forceinline__ unsigned short f2bf_fast(float x) {
    union { float f; unsigned int u; } v;
    v.f = x;
    return (unsigned short)((v.u + 0x8000u) >> 16);
}

// Kernel 1: vt layout [bn][lchunk=l>>3][h][l&7] bf16 -- so that phase-B B-operand
// loads are 16B/lane CONTIGUOUS across the 16 lanes of an MFMA column group
// (old layout was 16B at 1KB lane-stride = 64 lines/wave-load, 4x L2 overfetch).
__global__ __launch_bounds__(256) void vtrans_kernel(const float* __restrict__ v,
                                                     unsigned short* __restrict__ vt) {
    const int bid = blockIdx.x;
    const int tid = threadIdx.x;
    const int l0 = (bid & 7) * 64;
    const int h0 = ((bid >> 3) & 1) * 64;
    const int bn = bid >> 4;
    const int b = bn >> 3, n = bn & 7;
    __shared__ float tile[64][65];
    const float* vb = v + ((size_t)b * L_SEQ) * DINNER + n * HEADDIM_;
#pragma unroll
    for (int i = 0; i < 16; ++i) {
        int f = i * 256 + tid;
        int hh = f & 63, ll = f >> 6;
        tile[hh][ll] = vb[(size_t)(l0 + ll) * DINNER + (h0 + hh)];
    }
    __syncthreads();
    unsigned short* vdst = vt + (size_t)bn * (64 * 128 * 8);
#pragma unroll
    for (int i = 0; i < 2; ++i) {
        int f = i * 256 + tid;       // 512 groups of 8 shorts
        int hh = f & 63;             // h within tile (innermost -> coalesced stores)
        int lc = f >> 6;             // 0..7 l-chunk within tile
        short8 pk;
#pragma unroll
        for (int j = 0; j < 8; ++j)
            pk[j] = (short)f2bf_rne(tile[hh][lc * 8 + j]);
        *(short8*)(vdst + ((size_t)((l0 >> 3) + lc) * 128 + (h0 + hh)) * 8) = pk;
    }
}

// Kernel 2: fused k-part Chebyshev (phase A -> LDS, PER-WAVE l-range, no barrier)
// + q-part Chebyshev + MFMA. Block = 4 waves, 16 t-rows, one (b,n).
// l-permutation: chunk c, lane (w,quad), slot jj <-> l = w*128 + quad*32 + c*8 + jj.
// LDS: red[] UNION'd over ksl[] (red only live after last ksl read) ->
// 33.9 KB/block instead of 67.7 KB -> LDS allows 4 blocks/CU; bounds (256,3).
__global__ __launch_bounds__(256, 3) void vand_fused(const float* __restrict__ v,
                                                     const float* __restrict__ q,
                                                     const float* __restrict__ k,
                                                     const unsigned short* __restrict__ vt,
                                                     float* __restrict__ out) {
    const int tid  = threadIdx.x;
    const int w    = tid >> 6;
    const int lane = tid & 63;
    const int tl   = lane & 15;
    const int quad = lane >> 4;
    const int ttile = blockIdx.x;     // 0..31
    const int bn    = blockIdx.y;     // 0..15
    const int b = bn >> 3, n = bn & 7;
    const float t0f = (float)(ttile * 16);

    __shared__ float smem[16 * KS_ROW];         // 33.9 KB: ksl (phases A/B), red (epilogue)
    float* ksl = smem;

    // ---- Phase A: KS[t][l] for t in tile, l in THIS WAVE's 128-range ----
    // Wave w writes l in [w*128, w*128+128) and reads back only that range in
    // phase B -> same-wave ds ordering suffices, NO __syncthreads needed.
#pragma unroll
    for (int rep = 0; rep < 2; ++rep) {
        const int l = w * 128 + rep * 64 + lane;
        const float* krow = k + ((size_t)(b * L_SEQ + l)) * (NHEADS_ * QKD) + n * QKD;
        float kk[16];
#pragma unroll
        for (int d4 = 0; d4 < 4; ++d4) {
            float4 t4 = *(const float4*)(krow + 4 * d4);
            kk[d4 * 4 + 0] = t4.x; kk[d4 * 4 + 1] = t4.y;
            kk[d4 * 4 + 2] = t4.z; kk[d4 * 4 + 3] = t4.w;
        }
        float2v M2[8], C1[8], C0[8];
#pragma unroll
        for (int i = 0; i < 8; ++i) {
            float a0 = EPS_F * kk[2 * i], a1 = EPS_F * kk[2 * i + 1];
            M2[i].x = two_cos_small(a0);         M2[i].y = two_cos_small(a1);
            C1[i].x = cosrev(a0 * t0f);          C1[i].y = cosrev(a1 * t0f);
            C0[i].x = cosrev(a0 * (t0f - 1.f));  C0[i].y = cosrev(a1 * (t0f - 1.f));
        }
        const int base = (l >> 5) * 33 + (l & 31);
#pragma unroll
        for (int m = 0; m < 16; ++m) {
            float2v s = ((C1[0] + C1[1]) + (C1[2] + C1[3]))
                      + ((C1[4] + C1[5]) + (C1[6] + C1[7]));
            ksl[m * KS_ROW + base] = s.x + s.y;
#pragma unroll
            for (int i = 0; i < 8; ++i) {
                float2v nx = M2[i] * C1[i] - C0[i];
                C0[i] = C1[i];
                C1[i] = nx;
            }
        }
    }

    // ---- Phase B: q-part recurrence + subtract KS + MFMA ----
    const int   t   = ttile * 16 + tl;
    const int   l0  = w * 128 + quad * 32;
    const float l0f = (float)l0;

    const float* qrow = q + ((size_t)(b * L_SEQ + t)) * (NHEADS_ * QKD) + n * QKD;
    float2v M2[8], C1[8], C0[8];
#pragma unroll
    for (int d4 = 0; d4 < 4; ++d4) {
        float4 qq = *(const float4*)(qrow + 4 * d4);
        float aa[4] = {EPS_F * qq.x, EPS_F * qq.y, EPS_F * qq.z, EPS_F * qq.w};
#pragma unroll
        for (int e = 0; e < 2; ++e) {
            int i = d4 * 2 + e;
            float a0 = aa[2 * e], a1 = aa[2 * e + 1];
            M2[i].x = two_cos_small(a0);         M2[i].y = two_cos_small(a1);
            C1[i].x = cosrev(a0 * l0f);          C1[i].y = cosrev(a1 * l0f);
            C0[i].x = cosrev(a0 * (l0f - 1.f));  C0[i].y = cosrev(a1 * (l0f - 1.f));
        }
    }

    const unsigned short* vrow = vt + (size_t)bn * (64 * 128 * 8);
    const int vbaseoff = (w * 16 + quad * 4) * 1024 + tl * 8;   // shorts
    const int klds = tl * KS_ROW + (4 * w + quad) * 33;

    floatx4 acc[8] = {};

#pragma unroll
    for (int c = 0; c < 4; ++c) {
        float kv[8];
#pragma unroll
        for (int jj = 0; jj < 8; ++jj) kv[jj] = ksl[klds + c * 8 + jj];
        short8 af;
#pragma unroll
        for (int jj = 0; jj < 8; ++jj) {
            float2v sv = ((C1[0] + C1[1]) + (C1[2] + C1[3]))
                       + ((C1[4] + C1[5]) + (C1[6] + C1[7]));
            float s = (sv.x + sv.y) - kv[jj];
            af[jj] = (short)f2bf_fast(s);
#pragma unroll
            for (int i = 0; i < 8; ++i) {
                float2v nx = M2[i] * C1[i] - C0[i];
                C0[i] = C1[i];
                C1[i] = nx;
            }
        }
#pragma unroll
        for (int ht = 0; ht < 8; ++ht) {
            const short8 bfr = *(const short8*)((const short*)vrow +
                                  vbaseoff + c * 1024 + ht * 128);
            acc[ht] = __builtin_amdgcn_mfma_f32_16x16x32_bf16(af, bfr, acc[ht], 0, 0, 0);
        }
    }

    // ---- split-K reduction + epilogue (red overlays ksl; barrier both sides) ----
    __syncthreads();   // all waves done reading ksl before it is clobbered
    float (*red)[64][33] = (float (*)[64][33])smem;   // 4*64*33 = 8448 <= 16*529
#pragma unroll
    for (int ht = 0; ht < 8; ++ht)
#pragma unroll
        for (int r = 0; r < 4; ++r)
            red[w][lane][ht * 4 + r] = acc[ht][r];
    __syncthreads();

    const float* vbase = v   + ((size_t)b * L_SEQ) * DINNER + n * HEADDIM_;
    float*       obase = out + ((size_t)b * L_SEQ) * DINNER + n * HEADDIM_;
#pragma unroll
    for (int i = 0; i < 2; ++i) {
        int g    = i * 256 + tid;      // 512 float4 groups (16 t x 32 h-quads)
        int hb   = g & 31;             // h = hb*4 + e
        int tloc = g >> 5;             // 0..15
        int lidx0 = ((tloc >> 2) << 4) + ((hb & 3) << 2);
        int aidx  = ((hb >> 2) << 2) + (tloc & 3);
        float4 sum;
        float* sp = &sum.x;
#pragma unroll
        for (int e = 0; e < 4; ++e) {
            int lidx = lidx0 + e;
            sp[e] = (red[0][lidx][aidx] + red[1][lidx][aidx])
                  + (red[2][lidx][aidx] + red[3][lidx][aidx]);
        }
        size_t gi = (size_t)(ttile * 16 + tloc) * DINNER + hb * 4;
        float4 vres = *(const float4*)(vbase + gi);
        float4 o;
        o.x = fmaf(STD_F, sum.x, vres.x);
        o.y = fmaf(STD_F, sum.y, vres.y);
        o.z = fmaf(STD_F, sum.z, vres.z);
        o.w = fmaf(STD_F, sum.w, vres.w);
        *(float4*)(obase + gi) = o;
    }
}

extern "C" void kernel_launch(void* const* d_in, const int* in_sizes, int n_in,
                              void* d_out, int out_size, void* d_ws, size_t ws_size,
                              hipStream_t stream) {
    const float* v = (const float*)d_in[0];
    const float* q = (const float*)d_in[1];
    const float* k = (const float*)d_in[2];
    float* out = (float*)d_out;
    unsigned short* vt = (unsigned short*)d_ws;   // 16*64*128*8 bf16 = 2 MiB

    vtrans_kernel<<<dim3(256), 256, 0, stream>>>(v, vt);
    vand_fused<<<dim3(L_SEQ / 16, 16), 256, 0, stream>>>(v, q, k, vt, out);
}